// Round 2
// baseline (302.726 us; speedup 1.0000x reference)
//
#include <hip/hip_runtime.h>
#include <math.h>

// Problem constants (fixed by setup_inputs)
#define BB   32
#define CC   256
#define LL   4096
#define SS   8
#define CS   32
#define NT   512                 // threads per block (8 waves)
#define WV   (NT / 64)           // 8 waves
#define F4_ROW (LL / 4)          // 1024 float4 per row
#define F4_THR (F4_ROW / NT)     // 2 float4 per thread
#define NCH    (F4_ROW / 64)     // 16 contiguous 64-f4 chunks (one per wave,k)

__device__ __forceinline__ float gelu_exact(float x) {
    // exact gelu: x * 0.5 * (1 + erf(x / sqrt(2)))
    return 0.5f * x * (1.0f + erff(x * 0.70710678118654752440f));
}

// Workgroup barrier draining ONLY lgkmcnt (LDS). Global prefetch loads and
// epilogue stores stay in flight across it (vmcnt untouched). All cross-thread
// data flows through LDS, so this is sufficient.
__device__ __forceinline__ void lds_barrier() {
    asm volatile("s_waitcnt lgkmcnt(0)" ::: "memory");
    __builtin_amdgcn_s_barrier();
    asm volatile("" ::: "memory");
}

// Load one channel row: bulk float4 + per-chunk x halos.
// Halos: lane 0 of chunk needs x[4f-1], lane 63 needs x[4f+4] (0 at row ends).
// These are the ONLY cross-chunk x values; carrying them per-reader breaks the
// data dependence that would otherwise force a vmcnt drain before the barrier.
__device__ __forceinline__ void load_row(const float* __restrict__ rowf,
                                         int t, int lane,
                                         float4* x4, float* xhl, float* xhr) {
    const float4* row4 = (const float4*)rowf;
#pragma unroll
    for (int k = 0; k < F4_THR; ++k) {
        const int f = t + NT * k;
        x4[k] = row4[f];
        float hl = 0.0f, hr = 0.0f;
        if (lane == 0  && f > 0)          hl = rowf[4 * f - 1];
        if (lane == 63 && f < F4_ROW - 1) hr = rowf[4 * f + 4];
        xhl[k] = hl;
        xhr[k] = hr;
    }
}

__global__ __launch_bounds__(NT, 8)
void hdconv_encoder_kernel(const float* __restrict__ inp,
                           const float* __restrict__ conv_w,   // [S,3,CS]
                           const float* __restrict__ conv_b,   // [S,CS]
                           const float* __restrict__ ln_g,     // [L]
                           const float* __restrict__ ln_b,     // [L]
                           const float* __restrict__ pw_w,     // [C]
                           const float* __restrict__ pw_b,     // [C]
                           float* __restrict__ out) {
    // ln gamma/beta staged in LDS (frees 16 VGPRs -> 64-VGPR / 8-wave target).
    __shared__ float4 Gs[F4_ROW];        // 16 KiB
    __shared__ float4 Es[F4_ROW];        // 16 KiB
    // y-only chunk edges, double-buffered. Position order f = t + NT*k, so
    // chunk ordinal kw = k*WV + wave. eYl[p][1+kw] = y[last pos of chunk kw]
    // (lane 63), eYl[p][0] = 0 sentinel. eYr[p][kw] = y[first pos of chunk kw]
    // (lane 0), eYr[p][NCH] = 0 sentinel. Readers add their own x halo.
    __shared__ float eYl[2][NCH + 1];
    __shared__ float eYr[2][NCH + 1];
    __shared__ float red[2][2 * WV];     // per-wave {sum, sumsq}, double-buffered

    const int t    = threadIdx.x;
    const int blk  = blockIdx.x;      // [0, B*CS)
    const int b    = blk >> 5;        // batch
    const int c    = blk & 31;        // channel within group (block-uniform)
    const int lane = t & 63;
    const int wave = t >> 6;

    // ---- prologue: stage gamma/beta, zero edge buffers, load x_0 ----
    {
        const float4* gp = (const float4*)ln_g;
        const float4* ep = (const float4*)ln_b;
#pragma unroll
        for (int k = 0; k < F4_THR; ++k) {
            Gs[t + NT * k] = gp[t + NT * k];
            Es[t + NT * k] = ep[t + NT * k];
        }
    }
    if (t < NCH + 1) {
        eYl[0][t] = 0.0f; eYl[1][t] = 0.0f;   // y_{-1} = 0; sentinels stay 0
        eYr[0][t] = 0.0f; eYr[1][t] = 0.0f;
    }

    float y[4 * F4_THR];
#pragma unroll
    for (int j = 0; j < 4 * F4_THR; ++j) y[j] = 0.0f;

    float4 x4[F4_THR];
    float  xhl[F4_THR], xhr[F4_THR];
    load_row(inp + ((size_t)(b * CC + c)) * LL, t, lane, x4, xhl, xhr);

    lds_barrier();   // publishes Gs/Es + zeroed edges

    for (int i = 0; i < SS; ++i) {
        const int p  = i & 1;
        const int ch = i * CS + c;                        // global channel

        // ---- prefetch x_{i+1}: first consumer is NEXT iteration's conv.
        // Nothing before this iteration's barrier depends on it, and the
        // barrier doesn't drain vmcnt -> a full iteration of latency hiding.
        float4 xn4[F4_THR];
        float  xnl[F4_THR], xnr[F4_THR];
        if (i + 1 < SS)
            load_row(inp + ((size_t)(b * CC + ch + CS)) * LL, t, lane,
                     xn4, xnl, xnr);

        // block-uniform per-(group, c) params -> scalar loads
        const float w0  = conv_w[i * 96 + 0 * CS + c];
        const float w1  = conv_w[i * 96 + 1 * CS + c];
        const float w2  = conv_w[i * 96 + 2 * CS + c];
        const float bcv = conv_b[i * CS + c];

        // ---- 3-tap depthwise conv via shfl halos + LN partial sums ----
        float lsum = 0.0f, lsq = 0.0f;
#pragma unroll
        for (int k = 0; k < F4_THR; ++k) {
            const int kw = k * WV + wave;
            const float s0 = x4[k].x + y[4 * k + 0];
            const float s1 = x4[k].y + y[4 * k + 1];
            const float s2 = x4[k].z + y[4 * k + 2];
            const float s3 = x4[k].w + y[4 * k + 3];
            float sm1 = __shfl_up(s3, 1, 64);    // lane l-1's s3 == s[4f-1]
            float sp4 = __shfl_down(s0, 1, 64);  // lane l+1's s0 == s[4f+4]
            if (lane == 0)  sm1 = xhl[k] + eYl[p][kw];      // cross-chunk left
            if (lane == 63) sp4 = xhr[k] + eYr[p][kw + 1];  // cross-chunk right
            const float y0 = fmaf(w0, sm1, fmaf(w1, s0, fmaf(w2, s1, bcv)));
            const float y1 = fmaf(w0, s0,  fmaf(w1, s1, fmaf(w2, s2, bcv)));
            const float y2 = fmaf(w0, s1,  fmaf(w1, s2, fmaf(w2, s3, bcv)));
            const float y3 = fmaf(w0, s2,  fmaf(w1, s3, fmaf(w2, sp4, bcv)));
            y[4 * k + 0] = y0; y[4 * k + 1] = y1;
            y[4 * k + 2] = y2; y[4 * k + 3] = y3;
            lsum += (y0 + y1) + (y2 + y3);
            lsq  += fmaf(y0, y0, fmaf(y1, y1, fmaf(y2, y2, y3 * y3)));
            // y-only edges for iteration i+1 (other buffer). Pure VALU values:
            // no load dependence, so no vmcnt wait is forced before the barrier.
            if (lane == 63) eYl[p ^ 1][1 + kw] = y3;
            if (lane == 0)  eYr[p ^ 1][kw]     = y0;
        }

        // ---- wave reduce, cross-wave partials to LDS ----
#pragma unroll
        for (int off = 32; off > 0; off >>= 1) {
            lsum += __shfl_down(lsum, off, 64);
            lsq  += __shfl_down(lsq,  off, 64);
        }
        if (lane == 0) { red[p][wave * 2] = lsum; red[p][wave * 2 + 1] = lsq; }

        // ONE barrier per group: publishes red[p] and next-iteration y-edges.
        lds_barrier();

        // every thread folds the 8 wave-partials itself (broadcast LDS reads)
        const float sum = ((red[p][0]  + red[p][2])  + (red[p][4]  + red[p][6]))
                        + ((red[p][8]  + red[p][10]) + (red[p][12] + red[p][14]));
        const float sq  = ((red[p][1]  + red[p][3])  + (red[p][5]  + red[p][7]))
                        + ((red[p][9]  + red[p][11]) + (red[p][13] + red[p][15]));
        const float mean = sum * (1.0f / LL);
        const float var  = sq * (1.0f / LL) - mean * mean;
        const float inv  = rsqrtf(var + 1e-6f);

        // ---- normalize + pointwise scale/bias + exact gelu + residual ----
        const float pw = pw_w[ch];
        const float pb = pw_b[ch];
        float4* orow = (float4*)(out + ((size_t)(b * CC + ch)) * LL);
#pragma unroll
        for (int k = 0; k < F4_THR; ++k) {
            const float4 g = Gs[t + NT * k];
            const float4 e = Es[t + NT * k];
            float4 o;
            float n;
            n   = fmaf((y[4 * k + 0] - mean) * inv, g.x, e.x);
            o.x = x4[k].x + gelu_exact(fmaf(n, pw, pb));
            n   = fmaf((y[4 * k + 1] - mean) * inv, g.y, e.y);
            o.y = x4[k].y + gelu_exact(fmaf(n, pw, pb));
            n   = fmaf((y[4 * k + 2] - mean) * inv, g.z, e.z);
            o.z = x4[k].z + gelu_exact(fmaf(n, pw, pb));
            n   = fmaf((y[4 * k + 3] - mean) * inv, g.w, e.w);
            o.w = x4[k].w + gelu_exact(fmaf(n, pw, pb));
            orow[t + NT * k] = o;   // plain store: keep L3 write-back behavior
        }

        if (i + 1 < SS) {
#pragma unroll
            for (int k = 0; k < F4_THR; ++k) {
                x4[k] = xn4[k]; xhl[k] = xnl[k]; xhr[k] = xnr[k];
            }
        }
    }
}

extern "C" void kernel_launch(void* const* d_in, const int* in_sizes, int n_in,
                              void* d_out, int out_size, void* d_ws, size_t ws_size,
                              hipStream_t stream) {
    const float* inp    = (const float*)d_in[0];
    const float* conv_w = (const float*)d_in[1];
    const float* conv_b = (const float*)d_in[2];
    const float* ln_g   = (const float*)d_in[3];
    const float* ln_b   = (const float*)d_in[4];
    const float* pw_w   = (const float*)d_in[5];
    const float* pw_b   = (const float*)d_in[6];
    float* out = (float*)d_out;

    dim3 grid(BB * CS);   // 1024 blocks: one per (batch, within-group channel) chain
    dim3 block(NT);
    hdconv_encoder_kernel<<<grid, block, 0, stream>>>(
        inp, conv_w, conv_b, ln_g, ln_b, pw_w, pw_b, out);
}

// Round 3
// 277.595 us; speedup vs baseline: 1.0905x; 1.0905x over previous
//
#include <hip/hip_runtime.h>
#include <math.h>

// Problem constants (fixed by setup_inputs)
#define BB   32
#define CC   256
#define LL   4096
#define SS   8
#define CS   32
#define NT   512                 // threads per block (8 waves)
#define WV   (NT / 64)           // 8 waves
#define F4_ROW (LL / 4)          // 1024 float4 per row
#define F4_THR (F4_ROW / NT)     // 2 float4 per thread
#define NCH    (F4_ROW / 64)     // 16 contiguous 64-f4 chunks (one per wave,k)

__device__ __forceinline__ float gelu_exact(float x) {
    // exact gelu: x * 0.5 * (1 + erf(x / sqrt(2)))
    return 0.5f * x * (1.0f + erff(x * 0.70710678118654752440f));
}

// Workgroup barrier draining ONLY lgkmcnt (LDS). Global prefetch loads and
// epilogue stores stay in flight across it (vmcnt untouched). All cross-thread
// data flows through LDS, so this is sufficient.
__device__ __forceinline__ void lds_barrier() {
    asm volatile("s_waitcnt lgkmcnt(0)" ::: "memory");
    __builtin_amdgcn_s_barrier();
    asm volatile("" ::: "memory");
}

__global__ __launch_bounds__(NT)
__attribute__((amdgpu_waves_per_eu(8)))   // min 8 waves/SIMD -> VGPR budget 64
void hdconv_encoder_kernel(const float* __restrict__ inp,
                           const float* __restrict__ conv_w,   // [S,3,CS]
                           const float* __restrict__ conv_b,   // [S,CS]
                           const float* __restrict__ ln_g,     // [L]
                           const float* __restrict__ ln_b,     // [L]
                           const float* __restrict__ pw_w,     // [C]
                           const float* __restrict__ pw_b,     // [C]
                           float* __restrict__ out) {
    // ln gamma/beta staged in LDS (frees 16 VGPRs). 33 KiB/block -> 4 blocks/CU.
    __shared__ float4 Gs[F4_ROW];        // 16 KiB
    __shared__ float4 Es[F4_ROW];        // 16 KiB
    // y-only chunk edges, double-buffered. Position order f = t + NT*k, chunk
    // ordinal kw = k*WV + wave. eYl[p][1+kw] = y[last pos of chunk kw] (lane 63),
    // eYl[p][0] = 0 sentinel. eYr[p][kw] = y[first pos of chunk kw] (lane 0),
    // eYr[p][NCH] = 0 sentinel. Pure VALU values -> no vmcnt dependence before
    // the barrier; readers add their own x halo (fresh L2-warm scalar load).
    __shared__ float eYl[2][NCH + 1];
    __shared__ float eYr[2][NCH + 1];
    __shared__ float red[2][2 * WV];     // per-wave {sum, sumsq}, double-buffered

    const int t    = threadIdx.x;
    const int blk  = blockIdx.x;      // [0, B*CS)
    const int b    = blk >> 5;        // batch
    const int c    = blk & 31;        // channel within group (block-uniform)
    const int lane = t & 63;
    const int wave = t >> 6;

    // ---- prologue: stage gamma/beta, zero edge buffers, load x_0 ----
    {
        const float4* gp = (const float4*)ln_g;
        const float4* ep = (const float4*)ln_b;
#pragma unroll
        for (int k = 0; k < F4_THR; ++k) {
            Gs[t + NT * k] = gp[t + NT * k];
            Es[t + NT * k] = ep[t + NT * k];
        }
    }
    if (t < NCH + 1) {
        eYl[0][t] = 0.0f; eYl[1][t] = 0.0f;   // y_{-1} = 0; sentinels stay 0
        eYr[0][t] = 0.0f; eYr[1][t] = 0.0f;
    }

    float y[4 * F4_THR];
#pragma unroll
    for (int j = 0; j < 4 * F4_THR; ++j) y[j] = 0.0f;

    float4 x4[F4_THR];
    {
        const float4* row4 = (const float4*)(inp + ((size_t)(b * CC + c)) * LL);
#pragma unroll
        for (int k = 0; k < F4_THR; ++k) x4[k] = row4[t + NT * k];
    }

    lds_barrier();   // publishes Gs/Es + zeroed edges

    for (int i = 0; i < SS; ++i) {
        const int p  = i & 1;
        const int ch = i * CS + c;                        // global channel
        const float* rowc = inp + ((size_t)(b * CC + ch)) * LL;

        // ---- current-row x halos: 2 lane-predicated scalar loads per chunk.
        // This row was bulk-loaded by this block one iteration ago -> L1/L2
        // warm. Transient registers (live only through the conv), replacing
        // 8 persistent halo VGPRs.
        float xm1[F4_THR], xp4[F4_THR];
#pragma unroll
        for (int k = 0; k < F4_THR; ++k) {
            const int f = t + NT * k;
            xm1[k] = (lane == 0  && f > 0)          ? rowc[4 * f - 1] : 0.0f;
            xp4[k] = (lane == 63 && f < F4_ROW - 1) ? rowc[4 * f + 4] : 0.0f;
        }

        // ---- prefetch x_{i+1}: first consumer is NEXT iteration's conv.
        // The lgkm-only barrier doesn't drain vmcnt -> a full iteration of
        // latency hiding for these 2 dwordx4 loads.
        float4 xn4[F4_THR];
        if (i + 1 < SS) {
            const float4* xn = (const float4*)(rowc + (size_t)CS * LL);
#pragma unroll
            for (int k = 0; k < F4_THR; ++k) xn4[k] = xn[t + NT * k];
        }

        // block-uniform per-(group, c) params -> scalar loads
        const float w0  = conv_w[i * 96 + 0 * CS + c];
        const float w1  = conv_w[i * 96 + 1 * CS + c];
        const float w2  = conv_w[i * 96 + 2 * CS + c];
        const float bcv = conv_b[i * CS + c];

        // ---- 3-tap depthwise conv via shfl halos + LN partial sums ----
        float lsum = 0.0f, lsq = 0.0f;
#pragma unroll
        for (int k = 0; k < F4_THR; ++k) {
            const int kw = k * WV + wave;
            const float s0 = x4[k].x + y[4 * k + 0];
            const float s1 = x4[k].y + y[4 * k + 1];
            const float s2 = x4[k].z + y[4 * k + 2];
            const float s3 = x4[k].w + y[4 * k + 3];
            float sm1 = __shfl_up(s3, 1, 64);    // lane l-1's s3 == s[4f-1]
            float sp4 = __shfl_down(s0, 1, 64);  // lane l+1's s0 == s[4f+4]
            if (lane == 0)  sm1 = xm1[k] + eYl[p][kw];      // cross-chunk left
            if (lane == 63) sp4 = xp4[k] + eYr[p][kw + 1];  // cross-chunk right
            const float y0 = fmaf(w0, sm1, fmaf(w1, s0, fmaf(w2, s1, bcv)));
            const float y1 = fmaf(w0, s0,  fmaf(w1, s1, fmaf(w2, s2, bcv)));
            const float y2 = fmaf(w0, s1,  fmaf(w1, s2, fmaf(w2, s3, bcv)));
            const float y3 = fmaf(w0, s2,  fmaf(w1, s3, fmaf(w2, sp4, bcv)));
            y[4 * k + 0] = y0; y[4 * k + 1] = y1;
            y[4 * k + 2] = y2; y[4 * k + 3] = y3;
            lsum += (y0 + y1) + (y2 + y3);
            lsq  += fmaf(y0, y0, fmaf(y1, y1, fmaf(y2, y2, y3 * y3)));
            // y-only edges for iteration i+1 (other buffer); pure VALU values.
            if (lane == 63) eYl[p ^ 1][1 + kw] = y3;
            if (lane == 0)  eYr[p ^ 1][kw]     = y0;
        }

        // ---- wave reduce, cross-wave partials to LDS ----
#pragma unroll
        for (int off = 32; off > 0; off >>= 1) {
            lsum += __shfl_down(lsum, off, 64);
            lsq  += __shfl_down(lsq,  off, 64);
        }
        if (lane == 0) { red[p][wave * 2] = lsum; red[p][wave * 2 + 1] = lsq; }

        // ONE barrier per group: publishes red[p] and next-iteration y-edges.
        lds_barrier();

        // every thread folds the 8 wave-partials itself (broadcast LDS reads)
        const float sum = ((red[p][0]  + red[p][2])  + (red[p][4]  + red[p][6]))
                        + ((red[p][8]  + red[p][10]) + (red[p][12] + red[p][14]));
        const float sq  = ((red[p][1]  + red[p][3])  + (red[p][5]  + red[p][7]))
                        + ((red[p][9]  + red[p][11]) + (red[p][13] + red[p][15]));
        const float mean = sum * (1.0f / LL);
        const float var  = sq * (1.0f / LL) - mean * mean;
        const float inv  = rsqrtf(var + 1e-6f);

        // ---- normalize + pointwise scale/bias + exact gelu + residual ----
        const float pw = pw_w[ch];
        const float pb = pw_b[ch];
        float4* orow = (float4*)(out + ((size_t)(b * CC + ch)) * LL);
#pragma unroll
        for (int k = 0; k < F4_THR; ++k) {
            const float4 g = Gs[t + NT * k];
            const float4 e = Es[t + NT * k];
            float4 o;
            float n;
            n   = fmaf((y[4 * k + 0] - mean) * inv, g.x, e.x);
            o.x = x4[k].x + gelu_exact(fmaf(n, pw, pb));
            n   = fmaf((y[4 * k + 1] - mean) * inv, g.y, e.y);
            o.y = x4[k].y + gelu_exact(fmaf(n, pw, pb));
            n   = fmaf((y[4 * k + 2] - mean) * inv, g.z, e.z);
            o.z = x4[k].z + gelu_exact(fmaf(n, pw, pb));
            n   = fmaf((y[4 * k + 3] - mean) * inv, g.w, e.w);
            o.w = x4[k].w + gelu_exact(fmaf(n, pw, pb));
            orow[t + NT * k] = o;   // plain store: keep L3 write-back behavior
        }

        if (i + 1 < SS) {
#pragma unroll
            for (int k = 0; k < F4_THR; ++k) x4[k] = xn4[k];
        }
    }
}

extern "C" void kernel_launch(void* const* d_in, const int* in_sizes, int n_in,
                              void* d_out, int out_size, void* d_ws, size_t ws_size,
                              hipStream_t stream) {
    const float* inp    = (const float*)d_in[0];
    const float* conv_w = (const float*)d_in[1];
    const float* conv_b = (const float*)d_in[2];
    const float* ln_g   = (const float*)d_in[3];
    const float* ln_b   = (const float*)d_in[4];
    const float* pw_w   = (const float*)d_in[5];
    const float* pw_b   = (const float*)d_in[6];
    float* out = (float*)d_out;

    dim3 grid(BB * CS);   // 1024 blocks: one per (batch, within-group channel) chain
    dim3 block(NT);
    hdconv_encoder_kernel<<<grid, block, 0, stream>>>(
        inp, conv_w, conv_b, ln_g, ln_b, pw_w, pw_b, out);
}

// Round 7
// 247.672 us; speedup vs baseline: 1.2223x; 1.1208x over previous
//
#include <hip/hip_runtime.h>
#include <math.h>

// Problem constants (fixed by setup_inputs)
#define BB   32
#define CC   256
#define LL   4096
#define SS   8
#define CS   32
#define NT   512                 // threads per block (8 waves)
#define WV   (NT / 64)           // 8 waves
#define F4_ROW (LL / 4)          // 1024 float4 per row
#define F4_THR (F4_ROW / NT)     // 2 float4 per thread
#define NCH    (F4_ROW / 64)     // 16 contiguous 64-f4 chunks (one per wave,k)

__device__ __forceinline__ float gelu_exact(float x) {
    // exact gelu: x * 0.5 * (1 + erf(x / sqrt(2)))
    return 0.5f * x * (1.0f + erff(x * 0.70710678118654752440f));
}

// Workgroup barrier draining ONLY lgkmcnt (LDS). Global prefetch loads and
// epilogue stores stay in flight across it (vmcnt untouched). All cross-thread
// data flows through LDS, so this is sufficient.
__device__ __forceinline__ void lds_barrier() {
    asm volatile("s_waitcnt lgkmcnt(0)" ::: "memory");
    __builtin_amdgcn_s_barrier();
    asm volatile("" ::: "memory");
}

// Occupancy/VGPR law measured on this toolchain (rounds 0-3):
//   arch-VGPR budget = 256 / min_waves_per_EU.
//   (256,4)->64(ok)  (512,8)->32(spill)  waves_per_eu(8)->32(spill)
// So request 4 waves/EU -> 64-reg budget, which this kernel fits WITHOUT
// spilling. Runtime occupancy is set by ACTUAL usage (<=64 VGPR => 8 waves/
// SIMD possible); LDS 33 KiB/block -> 4 blocks/CU -> 32 waves/CU.
__global__ __launch_bounds__(NT, 4)
void hdconv_encoder_kernel(const float* __restrict__ inp,
                           const float* __restrict__ conv_w,   // [S,3,CS]
                           const float* __restrict__ conv_b,   // [S,CS]
                           const float* __restrict__ ln_g,     // [L]
                           const float* __restrict__ ln_b,     // [L]
                           const float* __restrict__ pw_w,     // [C]
                           const float* __restrict__ pw_b,     // [C]
                           float* __restrict__ out) {
    // ln gamma/beta staged in LDS (frees 16 VGPRs). 33 KiB/block -> 4 blocks/CU.
    __shared__ float4 Gs[F4_ROW];        // 16 KiB
    __shared__ float4 Es[F4_ROW];        // 16 KiB
    // y-only chunk edges, double-buffered. Position order f = t + NT*k, chunk
    // ordinal kw = k*WV + wave. eYl[p][1+kw] = y[last pos of chunk kw] (lane 63),
    // eYl[p][0] = 0 sentinel. eYr[p][kw] = y[first pos of chunk kw] (lane 0),
    // eYr[p][NCH] = 0 sentinel. Pure VALU values -> no vmcnt dependence before
    // the barrier; readers add their own x halo (fresh L2-warm scalar load).
    __shared__ float eYl[2][NCH + 1];
    __shared__ float eYr[2][NCH + 1];
    __shared__ float red[2][2 * WV];     // per-wave {sum, sumsq}, double-buffered

    const int t    = threadIdx.x;
    const int blk  = blockIdx.x;      // [0, B*CS)
    const int b    = blk >> 5;        // batch
    const int c    = blk & 31;        // channel within group (block-uniform)
    const int lane = t & 63;
    const int wave = t >> 6;

    // ---- prologue: stage gamma/beta, zero edge buffers, load x_0 ----
    {
        const float4* gp = (const float4*)ln_g;
        const float4* ep = (const float4*)ln_b;
#pragma unroll
        for (int k = 0; k < F4_THR; ++k) {
            Gs[t + NT * k] = gp[t + NT * k];
            Es[t + NT * k] = ep[t + NT * k];
        }
    }
    if (t < NCH + 1) {
        eYl[0][t] = 0.0f; eYl[1][t] = 0.0f;   // y_{-1} = 0; sentinels stay 0
        eYr[0][t] = 0.0f; eYr[1][t] = 0.0f;
    }

    float y[4 * F4_THR];
#pragma unroll
    for (int j = 0; j < 4 * F4_THR; ++j) y[j] = 0.0f;

    float4 x4[F4_THR];
    {
        const float4* row4 = (const float4*)(inp + ((size_t)(b * CC + c)) * LL);
#pragma unroll
        for (int k = 0; k < F4_THR; ++k) x4[k] = row4[t + NT * k];
    }

    lds_barrier();   // publishes Gs/Es + zeroed edges

    for (int i = 0; i < SS; ++i) {
        const int p  = i & 1;
        const int ch = i * CS + c;                        // global channel
        const float* rowc = inp + ((size_t)(b * CC + ch)) * LL;

        // ---- current-row x halos: 2 lane-predicated scalar loads per chunk.
        // This row was bulk-loaded by this block one iteration ago -> L1/L2
        // warm. Transient registers (live only through the conv).
        float xm1[F4_THR], xp4[F4_THR];
#pragma unroll
        for (int k = 0; k < F4_THR; ++k) {
            const int f = t + NT * k;
            xm1[k] = (lane == 0  && f > 0)          ? rowc[4 * f - 1] : 0.0f;
            xp4[k] = (lane == 63 && f < F4_ROW - 1) ? rowc[4 * f + 4] : 0.0f;
        }

        // ---- prefetch x_{i+1}: first consumer is NEXT iteration's conv.
        // The lgkm-only barrier doesn't drain vmcnt -> a full iteration of
        // latency hiding for these 2 dwordx4 loads.
        float4 xn4[F4_THR];
        if (i + 1 < SS) {
            const float4* xn = (const float4*)(rowc + (size_t)CS * LL);
#pragma unroll
            for (int k = 0; k < F4_THR; ++k) xn4[k] = xn[t + NT * k];
        }

        // block-uniform per-(group, c) params -> scalar loads
        const float w0  = conv_w[i * 96 + 0 * CS + c];
        const float w1  = conv_w[i * 96 + 1 * CS + c];
        const float w2  = conv_w[i * 96 + 2 * CS + c];
        const float bcv = conv_b[i * CS + c];

        // ---- 3-tap depthwise conv via shfl halos + LN partial sums ----
        float lsum = 0.0f, lsq = 0.0f;
#pragma unroll
        for (int k = 0; k < F4_THR; ++k) {
            const int kw = k * WV + wave;
            const float s0 = x4[k].x + y[4 * k + 0];
            const float s1 = x4[k].y + y[4 * k + 1];
            const float s2 = x4[k].z + y[4 * k + 2];
            const float s3 = x4[k].w + y[4 * k + 3];
            float sm1 = __shfl_up(s3, 1, 64);    // lane l-1's s3 == s[4f-1]
            float sp4 = __shfl_down(s0, 1, 64);  // lane l+1's s0 == s[4f+4]
            if (lane == 0)  sm1 = xm1[k] + eYl[p][kw];      // cross-chunk left
            if (lane == 63) sp4 = xp4[k] + eYr[p][kw + 1];  // cross-chunk right
            const float y0 = fmaf(w0, sm1, fmaf(w1, s0, fmaf(w2, s1, bcv)));
            const float y1 = fmaf(w0, s0,  fmaf(w1, s1, fmaf(w2, s2, bcv)));
            const float y2 = fmaf(w0, s1,  fmaf(w1, s2, fmaf(w2, s3, bcv)));
            const float y3 = fmaf(w0, s2,  fmaf(w1, s3, fmaf(w2, sp4, bcv)));
            y[4 * k + 0] = y0; y[4 * k + 1] = y1;
            y[4 * k + 2] = y2; y[4 * k + 3] = y3;
            lsum += (y0 + y1) + (y2 + y3);
            lsq  += fmaf(y0, y0, fmaf(y1, y1, fmaf(y2, y2, y3 * y3)));
            // y-only edges for iteration i+1 (other buffer); pure VALU values.
            if (lane == 63) eYl[p ^ 1][1 + kw] = y3;
            if (lane == 0)  eYr[p ^ 1][kw]     = y0;
        }

        // ---- wave reduce, cross-wave partials to LDS ----
#pragma unroll
        for (int off = 32; off > 0; off >>= 1) {
            lsum += __shfl_down(lsum, off, 64);
            lsq  += __shfl_down(lsq,  off, 64);
        }
        if (lane == 0) { red[p][wave * 2] = lsum; red[p][wave * 2 + 1] = lsq; }

        // ONE barrier per group: publishes red[p] and next-iteration y-edges.
        lds_barrier();

        // every thread folds the 8 wave-partials itself (broadcast LDS reads)
        const float sum = ((red[p][0]  + red[p][2])  + (red[p][4]  + red[p][6]))
                        + ((red[p][8]  + red[p][10]) + (red[p][12] + red[p][14]));
        const float sq  = ((red[p][1]  + red[p][3])  + (red[p][5]  + red[p][7]))
                        + ((red[p][9]  + red[p][11]) + (red[p][13] + red[p][15]));
        const float mean = sum * (1.0f / LL);
        const float var  = sq * (1.0f / LL) - mean * mean;
        const float inv  = rsqrtf(var + 1e-6f);

        // ---- normalize + pointwise scale/bias + exact gelu + residual ----
        const float pw = pw_w[ch];
        const float pb = pw_b[ch];
        float4* orow = (float4*)(out + ((size_t)(b * CC + ch)) * LL);
#pragma unroll
        for (int k = 0; k < F4_THR; ++k) {
            const float4 g = Gs[t + NT * k];
            const float4 e = Es[t + NT * k];
            float4 o;
            float n;
            n   = fmaf((y[4 * k + 0] - mean) * inv, g.x, e.x);
            o.x = x4[k].x + gelu_exact(fmaf(n, pw, pb));
            n   = fmaf((y[4 * k + 1] - mean) * inv, g.y, e.y);
            o.y = x4[k].y + gelu_exact(fmaf(n, pw, pb));
            n   = fmaf((y[4 * k + 2] - mean) * inv, g.z, e.z);
            o.z = x4[k].z + gelu_exact(fmaf(n, pw, pb));
            n   = fmaf((y[4 * k + 3] - mean) * inv, g.w, e.w);
            o.w = x4[k].w + gelu_exact(fmaf(n, pw, pb));
            orow[t + NT * k] = o;   // plain store: keep L3 write-back behavior
        }

        if (i + 1 < SS) {
#pragma unroll
            for (int k = 0; k < F4_THR; ++k) x4[k] = xn4[k];
        }
    }
}

extern "C" void kernel_launch(void* const* d_in, const int* in_sizes, int n_in,
                              void* d_out, int out_size, void* d_ws, size_t ws_size,
                              hipStream_t stream) {
    const float* inp    = (const float*)d_in[0];
    const float* conv_w = (const float*)d_in[1];
    const float* conv_b = (const float*)d_in[2];
    const float* ln_g   = (const float*)d_in[3];
    const float* ln_b   = (const float*)d_in[4];
    const float* pw_w   = (const float*)d_in[5];
    const float* pw_b   = (const float*)d_in[6];
    float* out = (float*)d_out;

    dim3 grid(BB * CS);   // 1024 blocks: one per (batch, within-group channel) chain
    dim3 block(NT);
    hdconv_encoder_kernel<<<grid, block, 0, stream>>>(
        inp, conv_w, conv_b, ln_g, ln_b, pw_w, pw_b, out);
}